// Round 2
// baseline (134.808 us; speedup 1.0000x reference)
//
#include <hip/hip_runtime.h>
#include <hip/hip_bf16.h>

#define N_OBJ   32
#define G_TOTAL 4960      // C(32,3)
#define GPAD    5120      // padded K (only k<4960 ever read by GEMM)
#define N_FILT  16
#define REL_D   16
#define BATCH   32
#define NQ      512
#define ZBLK    31        // 4960 = 31 * 160 exactly
#define KCH     160       // K-chunk (g's) per z-block
#define BPAD    184       // padded B-tile k-stride in u16: 368 B = 16-B aligned rows

typedef __attribute__((ext_vector_type(8))) short bf16x8;
typedef __attribute__((ext_vector_type(4))) float f32x4;

static __device__ inline unsigned short f2bf(float x) {
    union { float f; unsigned int u; } v; v.f = x;
    unsigned int r = v.u + 0x7fffu + ((v.u >> 16) & 1u);   // RNE
    return (unsigned short)(r >> 16);
}
static __device__ inline float bfbits2f(unsigned int bits) {
    union { unsigned int u; float f; } v; v.u = bits; return v.f;
}
// unrank lexicographic 3-combination of 32
static __device__ inline void unrank3(int g, int& a, int& b, int& c) {
    int rem = g;
    for (a = 0; a < 30; a++) { int cnt = ((31 - a) * (30 - a)) >> 1; if (rem < cnt) break; rem -= cnt; }
    for (b = a + 1; b < 31; b++) { if (rem < 31 - b) break; rem -= 31 - b; }
    c = b + 1 + rem;
}

// ===== L1: normw (blocks 0..511) + pairconv (512..1663) + zero-out (1664..1679) ===
__global__ __launch_bounds__(256) void k_front(const float* __restrict__ logits,
                                               const float* __restrict__ inputs,
                                               const float* __restrict__ filters,
                                               unsigned short* __restrict__ normw,
                                               unsigned short* __restrict__ D,
                                               float* __restrict__ out) {
    __shared__ __align__(16) char smem[11648];
    int t = threadIdx.x;
    int role = blockIdx.x;

    if (role < NQ) {
        // ---------- normw: softplus -> triple product -> softmax -> bf16, K-padded --
        float* sp  = (float*)smem;                            // 32 floats
        float* red = (float*)(smem + 128);                    // 4 floats
        unsigned short* wrow = (unsigned short*)(smem + 144); // 5120 u16
        int q = role;
        if (t < N_OBJ) {
            float x = logits[q * N_OBJ + t];
            sp[t] = (x > 15.f) ? x : log1pf(expf(x));
        }
        if (t < GPAD - G_TOTAL) wrow[G_TOTAL + t] = 0;        // zero the K-pad
        __syncthreads();

        int g0 = t * 20;
        int aa, bb, cc;
        unrank3(g0, aa, bb, cc);

        float w[20];
        float lmax = -1e30f;
#pragma unroll
        for (int k = 0; k < 20; k++) {
            float v = -1e30f;
            if (g0 + k < G_TOTAL) v = sp[aa] * sp[bb] * sp[cc];
            w[k] = v;
            lmax = fmaxf(lmax, v);
            cc++;
            if (cc >= 32) { bb++; cc = bb + 1; if (cc >= 32) { aa++; bb = aa + 1; cc = bb + 1; } }
        }
#pragma unroll
        for (int off = 32; off; off >>= 1) lmax = fmaxf(lmax, __shfl_down(lmax, off, 64));
        if ((t & 63) == 0) red[t >> 6] = lmax;
        __syncthreads();
        float wmax = fmaxf(fmaxf(red[0], red[1]), fmaxf(red[2], red[3]));

        float lsum = 0.f;
#pragma unroll
        for (int k = 0; k < 20; k++) {
            float e = (g0 + k < G_TOTAL) ? expf(w[k] - wmax) : 0.f;
            w[k] = e;
            lsum += e;
        }
#pragma unroll
        for (int off = 32; off; off >>= 1) lsum += __shfl_down(lsum, off, 64);
        __syncthreads();
        if ((t & 63) == 0) red[t >> 6] = lsum;
        __syncthreads();
        float inv = 1.f / (red[0] + red[1] + red[2] + red[3]);

#pragma unroll
        for (int k = 0; k < 20; k++)
            if (g0 + k < G_TOTAL) wrow[g0 + k] = f2bf(w[k] * inv);
        __syncthreads();
        // coalesced padded row write: 5120 u16 = 640 uint4
        uint4* dstrow = (uint4*)(normw + (size_t)q * GPAD);
        const uint4* srow = (const uint4*)wrow;
        for (int i = t; i < 640; i += 256) dstrow[i] = srow[i];
    } else if (role < NQ + 1152) {
        // ---------- pairconv: D[xy][p][b*16+f] = dot_d(inputs[b,x,y,:], filters[f,p,:])
        float* flt = (float*)smem;            // [f][p_pad] 16*180 floats
        int bid = role - NQ;                  // 0..1151
        int p = bid >> 7;                     // 0..8
        int xb = bid & 127;
        for (int i = t; i < 576; i += 256) {
            int i4 = i * 4;
            int f = i4 / 144;
            int r = i4 - f * 144;
            *(float4*)&flt[f * 180 + (r >> 4) * 20 + (r & 15)] = *(const float4*)(filters + i4);
        }
        __syncthreads();

        int row = xb * 256 + t;               // b*1024 + xy
        const float4* src = (const float4*)(inputs + (size_t)row * 16);
        float4 s0 = src[0], s1 = src[1], s2 = src[2], s3 = src[3];

        unsigned short outv[16];
        const float* fb = &flt[p * 20];
        int xy = row & 1023, b = row >> 10;
#pragma unroll
        for (int f = 0; f < 16; f++) {
            float4 f0 = *(const float4*)(fb + f * 180);
            float4 f1 = *(const float4*)(fb + f * 180 + 4);
            float4 f2 = *(const float4*)(fb + f * 180 + 8);
            float4 f3 = *(const float4*)(fb + f * 180 + 12);
            float d = s0.x * f0.x + s0.y * f0.y + s0.z * f0.z + s0.w * f0.w;
            d += s1.x * f1.x + s1.y * f1.y + s1.z * f1.z + s1.w * f1.w;
            d += s2.x * f2.x + s2.y * f2.y + s2.z * f2.z + s2.w * f2.w;
            d += s3.x * f3.x + s3.y * f3.y + s3.z * f3.z + s3.w * f3.w;
            outv[f] = f2bf(d);
        }
        uint4* dst = (uint4*)(D + ((size_t)(xy * 9 + p)) * 512 + b * 16);
        dst[0] = ((uint4*)outv)[0];
        dst[1] = ((uint4*)outv)[1];
    } else {
        // ---------- zero the output (atomics in k_back accumulate into it) ----------
        int zb = role - (NQ + 1152);          // 0..15
        uint4 zz; zz.x = zz.y = zz.z = zz.w = 0u;
        uint4* dst = (uint4*)out + (size_t)zb * 4096;
#pragma unroll
        for (int k = 0; k < 16; k++) dst[k * 256 + t] = zz;
    }
}

// ===== L2: fused gather + GEMM + atomic-reduce ====================================
// grid (8 n-tiles of 64, 31 z-chunks of 160 g). Each block:
//   phase 1: unrank its 160 groups
//   phase 2: gather B-tile[64 n][160 g] bf16 directly from D into LDS (padded rows)
//   phase 3: 4 waves (2 q-halves x 2 n-halves): acc 256q x 32n per wave,
//            A-frags straight from global normw (L2-resident), B from LDS,
//            atomicAdd into out (31 adds per output element across z)
__global__ __launch_bounds__(256, 1) void k_back(const unsigned short* __restrict__ A,
                                                 const unsigned short* __restrict__ D,
                                                 float* __restrict__ out) {
    __shared__ int tri[KCH];
    __shared__ __align__(16) unsigned short Bs[64][BPAD];
    int t = threadIdx.x;
    int n0 = blockIdx.x;           // 0..7
    int z  = blockIdx.y;           // 0..30
    int g0 = z * KCH;

    if (t < KCH) {
        int a, b, c; unrank3(g0 + t, a, b, c);
        tri[t] = a | (b << 8) | (c << 16);
    }
    __syncthreads();

    // ---- gather: thread (nsub=t&31 -> n-pair, gslot=t>>5 -> 20 g) ----
    int nsub = t & 31;
    int gslot = t >> 5;
    const unsigned short* dbase = D + n0 * 64 + 2 * nsub;
#pragma unroll 1
    for (int gp = 0; gp < 10; gp++) {
        int gl = gslot * 20 + gp * 2;
        float x0[2], x1[2];
#pragma unroll
        for (int gg = 0; gg < 2; gg++) {
            int pk = tri[gl + gg];
            int xs[3] = { pk & 255, (pk >> 8) & 255, (pk >> 16) & 255 };
            float a0 = 0.f, a1 = 0.f;
#pragma unroll
            for (int i = 0; i < 3; i++)
#pragma unroll
                for (int j = 0; j < 3; j++) {
                    unsigned int v = *(const unsigned int*)(dbase +
                        (size_t)((xs[i] * 32 + xs[j]) * 9 + i * 3 + j) * 512);
                    a0 += bfbits2f(v << 16);
                    a1 += bfbits2f(v & 0xffff0000u);
                }
            x0[gg] = a0; x1[gg] = a1;
        }
        unsigned int p0 = f2bf(x0[0]) | ((unsigned int)f2bf(x0[1]) << 16);
        unsigned int p1 = f2bf(x1[0]) | ((unsigned int)f2bf(x1[1]) << 16);
        *(unsigned int*)&Bs[2 * nsub][gl]     = p0;
        *(unsigned int*)&Bs[2 * nsub + 1][gl] = p1;
    }
    __syncthreads();

    // ---- GEMM: wave w: q-half qh = w&1 (256 q), n-half nh = w>>1 (32 n) ----
    int wave = t >> 6, lane = t & 63;
    int qh = wave & 1, nh = wave >> 1;
    int row16 = lane & 15, quad = lane >> 4;

    f32x4 acc[16][2] = {};
    const unsigned short* arow = A + (size_t)(qh * 256 + row16) * GPAD + g0 + quad * 8;
    const unsigned short* b0p = &Bs[nh * 32 + row16][quad * 8];
    const unsigned short* b1p = &Bs[nh * 32 + 16 + row16][quad * 8];

#pragma unroll 1
    for (int it = 0; it < 5; it++) {
        bf16x8 bfr0 = *(const bf16x8*)(b0p + it * 32);
        bf16x8 bfr1 = *(const bf16x8*)(b1p + it * 32);
#pragma unroll
        for (int qf = 0; qf < 16; qf++) {
            bf16x8 afr = *(const bf16x8*)(arow + (size_t)qf * (16 * GPAD) + it * 32);
            acc[qf][0] = __builtin_amdgcn_mfma_f32_16x16x32_bf16(afr, bfr0, acc[qf][0], 0, 0, 0);
            acc[qf][1] = __builtin_amdgcn_mfma_f32_16x16x32_bf16(afr, bfr1, acc[qf][1], 0, 0, 0);
        }
    }

    // ---- epilogue: atomic accumulate into out[b][q][f]; b const per (wave,nf) ----
    int bbase = n0 * 4 + nh * 2;
#pragma unroll
    for (int qf = 0; qf < 16; qf++) {
        int qb = qh * 256 + qf * 16 + quad * 4;
#pragma unroll
        for (int nf = 0; nf < 2; nf++) {
            float* o = out + (size_t)(bbase + nf) * (NQ * REL_D) + row16;
#pragma unroll
            for (int r = 0; r < 4; r++)
                atomicAdd(o + (qb + r) * REL_D, acc[qf][nf][r]);
        }
    }
}

extern "C" void kernel_launch(void* const* d_in, const int* in_sizes, int n_in,
                              void* d_out, int out_size, void* d_ws, size_t ws_size,
                              hipStream_t stream) {
    const float* inputs  = (const float*)d_in[0];   // (32,32,32,16)
    const float* logits  = (const float*)d_in[1];   // (512,32)
    const float* filters = (const float*)d_in[2];   // (16,3,3,16)
    float* out = (float*)d_out;                     // (32,512,16)

    char* ws = (char*)d_ws;
    unsigned short* normw = (unsigned short*)ws;                 //  5,242,880 B
    unsigned short* D     = (unsigned short*)(ws + 5242880);     //  9,437,184 B

    k_front<<<NQ + 1152 + 16, 256, 0, stream>>>(logits, inputs, filters, normw, D, out);
    k_back<<<dim3(8, ZBLK), 256, 0, stream>>>(normw, D, out);
}

// Round 3
// 102.555 us; speedup vs baseline: 1.3145x; 1.3145x over previous
//
#include <hip/hip_runtime.h>
#include <hip/hip_bf16.h>

#define N_OBJ   32
#define G_TOTAL 4960      // C(32,3)
#define GPAD    5120      // K padded to 32*160 for clean split-K
#define N_FILT  16
#define REL_D   16
#define BATCH   32
#define NQ      512
#define ZSPLIT  16
#define KCH     320       // GPAD / ZSPLIT
#define NIT     10        // KCH / 32

typedef __attribute__((ext_vector_type(8))) short bf16x8;
typedef __attribute__((ext_vector_type(4))) float f32x4;

static __device__ inline unsigned short f2bf(float x) {
    union { float f; unsigned int u; } v; v.f = x;
    unsigned int r = v.u + 0x7fffu + ((v.u >> 16) & 1u);   // RNE
    return (unsigned short)(r >> 16);
}
static __device__ inline float bfbits2f(unsigned int bits) {
    union { unsigned int u; float f; } v; v.u = bits; return v.f;
}
static __device__ inline void gload_lds16(const void* g, void* l) {
    __builtin_amdgcn_global_load_lds(
        (const __attribute__((address_space(1))) unsigned int*)g,
        (__attribute__((address_space(3))) unsigned int*)(unsigned int)(uintptr_t)l,
        16, 0, 0);
}
// unrank lexicographic 3-combination of 32
static __device__ inline void unrank3(int g, int& a, int& b, int& c) {
    int rem = g;
    for (a = 0; a < 30; a++) { int cnt = ((31 - a) * (30 - a)) >> 1; if (rem < cnt) break; rem -= cnt; }
    for (b = a + 1; b < 31; b++) { if (rem < 31 - b) break; rem -= 31 - b; }
    c = b + 1 + rem;
}

// ===== L1: normw (0..511) + pairconv (512..1663) + zero out & relT-pad (1664..1679)
__global__ __launch_bounds__(256) void k_front(const float* __restrict__ logits,
                                               const float* __restrict__ inputs,
                                               const float* __restrict__ filters,
                                               unsigned short* __restrict__ normw,
                                               unsigned short* __restrict__ D,
                                               unsigned short* __restrict__ relT,
                                               float* __restrict__ out) {
    __shared__ __align__(16) char smem[11648];
    int t = threadIdx.x;
    int role = blockIdx.x;

    if (role < NQ) {
        // ---------- normw: softplus -> triple product -> softmax -> bf16, K-padded --
        float* sp  = (float*)smem;                            // 32 floats
        float* red = (float*)(smem + 128);                    // 4 floats
        unsigned short* wrow = (unsigned short*)(smem + 144); // 5120 u16
        int q = role;
        if (t < N_OBJ) {
            float x = logits[q * N_OBJ + t];
            sp[t] = (x > 15.f) ? x : log1pf(expf(x));
        }
        if (t < GPAD - G_TOTAL) wrow[G_TOTAL + t] = 0;        // zero the K-pad
        __syncthreads();

        int g0 = t * 20;
        int aa, bb, cc;
        unrank3(g0, aa, bb, cc);

        float w[20];
        float lmax = -1e30f;
#pragma unroll
        for (int k = 0; k < 20; k++) {
            float v = -1e30f;
            if (g0 + k < G_TOTAL) v = sp[aa] * sp[bb] * sp[cc];
            w[k] = v;
            lmax = fmaxf(lmax, v);
            cc++;
            if (cc >= 32) { bb++; cc = bb + 1; if (cc >= 32) { aa++; bb = aa + 1; cc = bb + 1; } }
        }
#pragma unroll
        for (int off = 32; off; off >>= 1) lmax = fmaxf(lmax, __shfl_down(lmax, off, 64));
        if ((t & 63) == 0) red[t >> 6] = lmax;
        __syncthreads();
        float wmax = fmaxf(fmaxf(red[0], red[1]), fmaxf(red[2], red[3]));

        float lsum = 0.f;
#pragma unroll
        for (int k = 0; k < 20; k++) {
            float e = (g0 + k < G_TOTAL) ? expf(w[k] - wmax) : 0.f;
            w[k] = e;
            lsum += e;
        }
#pragma unroll
        for (int off = 32; off; off >>= 1) lsum += __shfl_down(lsum, off, 64);
        __syncthreads();
        if ((t & 63) == 0) red[t >> 6] = lsum;
        __syncthreads();
        float inv = 1.f / (red[0] + red[1] + red[2] + red[3]);

#pragma unroll
        for (int k = 0; k < 20; k++)
            if (g0 + k < G_TOTAL) wrow[g0 + k] = f2bf(w[k] * inv);
        __syncthreads();
        // coalesced padded row write: 5120 u16 = 640 uint4
        uint4* dstrow = (uint4*)(normw + (size_t)q * GPAD);
        const uint4* srow = (const uint4*)wrow;
        for (int i = t; i < 640; i += 256) dstrow[i] = srow[i];
    } else if (role < NQ + 1152) {
        // ---------- pairconv: D[xy][p][b*16+f] = dot_d(inputs[b,x,y,:], filters[f,p,:])
        float* flt = (float*)smem;            // [f][p_pad] 16*180 floats
        int bid = role - NQ;                  // 0..1151
        int p = bid >> 7;                     // 0..8
        int xb = bid & 127;
        for (int i = t; i < 576; i += 256) {
            int i4 = i * 4;
            int f = i4 / 144;
            int r = i4 - f * 144;
            *(float4*)&flt[f * 180 + (r >> 4) * 20 + (r & 15)] = *(const float4*)(filters + i4);
        }
        __syncthreads();

        int row = xb * 256 + t;               // b*1024 + xy
        const float4* src = (const float4*)(inputs + (size_t)row * 16);
        float4 s0 = src[0], s1 = src[1], s2 = src[2], s3 = src[3];

        unsigned short outv[16];
        const float* fb = &flt[p * 20];
        int xy = row & 1023, b = row >> 10;
#pragma unroll
        for (int f = 0; f < 16; f++) {
            float4 f0 = *(const float4*)(fb + f * 180);
            float4 f1 = *(const float4*)(fb + f * 180 + 4);
            float4 f2 = *(const float4*)(fb + f * 180 + 8);
            float4 f3 = *(const float4*)(fb + f * 180 + 12);
            float d = s0.x * f0.x + s0.y * f0.y + s0.z * f0.z + s0.w * f0.w;
            d += s1.x * f1.x + s1.y * f1.y + s1.z * f1.z + s1.w * f1.w;
            d += s2.x * f2.x + s2.y * f2.y + s2.z * f2.z + s2.w * f2.w;
            d += s3.x * f3.x + s3.y * f3.y + s3.z * f3.z + s3.w * f3.w;
            outv[f] = f2bf(d);
        }
        uint4* dst = (uint4*)(D + ((size_t)(xy * 9 + p)) * 512 + b * 16);
        dst[0] = ((uint4*)outv)[0];
        dst[1] = ((uint4*)outv)[1];
    } else {
        // ---------- zero out (atomics accumulate into it) + zero relT K-pad --------
        int zb = role - (NQ + 1152);          // 0..15
        uint4 zz; zz.x = zz.y = zz.z = zz.w = 0u;
        uint4* dst = (uint4*)out + (size_t)zb * 4096;
#pragma unroll
        for (int k = 0; k < 16; k++) dst[k * 256 + t] = zz;
        // relT pad columns 4960..5119, 32 rows per block: 8 lanes x 10 uints per row
        int row = zb * 32 + (t >> 3);
        unsigned int* prow = (unsigned int*)(relT + (size_t)row * GPAD + G_TOTAL);
#pragma unroll
        for (int k = 0; k < 10; k++) prow[(t & 7) * 10 + k] = 0u;
    }
}

// ===== L2: gather 9 pairs -> relT[n=b*16+f][g]  (620 blocks, 8 g each) ============
__global__ __launch_bounds__(256) void k_mid(const unsigned short* __restrict__ D,
                                             unsigned short* __restrict__ relT) {
    __shared__ int tri[8];
    int t = threadIdx.x;
    int g0 = blockIdx.x * 8;
    if (t < 8) {
        int a, b, c;
        unrank3(g0 + t, a, b, c);
        tri[t] = a | (b << 8) | (c << 16);
    }
    __syncthreads();

    float s0[8], s1[8];
#pragma unroll
    for (int g = 0; g < 8; g++) {
        int pk = tri[g];
        int xs[3] = { pk & 255, (pk >> 8) & 255, (pk >> 16) & 255 };
        float x0 = 0.f, x1 = 0.f;
#pragma unroll
        for (int i = 0; i < 3; i++)
#pragma unroll
            for (int j = 0; j < 3; j++) {
                int xy = xs[i] * 32 + xs[j];
                unsigned int v = *(const unsigned int*)(D + (size_t)(xy * 9 + i * 3 + j) * 512 + t * 2);
                x0 += bfbits2f(v << 16);
                x1 += bfbits2f(v & 0xffff0000u);
            }
        s0[g] = x0; s1[g] = x1;
    }
    unsigned int pack0[4], pack1[4];
#pragma unroll
    for (int k = 0; k < 4; k++) {
        pack0[k] = f2bf(s0[2 * k]) | ((unsigned int)f2bf(s0[2 * k + 1]) << 16);
        pack1[k] = f2bf(s1[2 * k]) | ((unsigned int)f2bf(s1[2 * k + 1]) << 16);
    }
    *(uint4*)(relT + (size_t)(2 * t) * GPAD + g0)     = *(uint4*)pack0;
    *(uint4*)(relT + (size_t)(2 * t + 1) * GPAD + g0) = *(uint4*)pack1;
}

// ===== L3: split-K GEMM, atomicAdd epilogue straight into out =====================
__global__ __launch_bounds__(256) void k_gemm(const unsigned short* __restrict__ A,
                                              const unsigned short* __restrict__ Bm,
                                              float* __restrict__ out) {
    __shared__ __align__(16) unsigned short As[2][64 * 32];
    __shared__ __align__(16) unsigned short Bs[2][64 * 32];
    int tid = threadIdx.x;
    int q0 = blockIdx.x * 64, n0 = blockIdx.y * 64, z = blockIdx.z;
    int k0 = z * KCH;
    int wave = tid >> 6, lane = tid & 63;
    int wm = wave & 1, wn = wave >> 1;
    int row16 = lane & 15, quad = lane >> 4;

    int srow = tid >> 2;
    int schunk = (tid & 3) ^ ((srow >> 1) & 3);
    const unsigned short* ga = A + (size_t)(q0 + srow) * GPAD + k0 + schunk * 8;
    const unsigned short* gb = Bm + (size_t)(n0 + srow) * GPAD + k0 + schunk * 8;
    char* lA = (char*)&As[0][0] + tid * 16;
    char* lB = (char*)&Bs[0][0] + tid * 16;

    f32x4 acc[2][2] = {};
    int fchunk = (quad ^ ((row16 >> 1) & 3)) * 8;

    gload_lds16(ga, lA);
    gload_lds16(gb, lB);
    for (int it = 0; it < NIT; ++it) {
        __syncthreads();
        if (it + 1 < NIT) {
            int nb = (it + 1) & 1;
            gload_lds16(ga + (it + 1) * 32, lA + nb * 64 * 32 * 2);
            gload_lds16(gb + (it + 1) * 32, lB + nb * 64 * 32 * 2);
        }
        int buf = it & 1;
        bf16x8 afr[2], bfr[2];
#pragma unroll
        for (int mi = 0; mi < 2; mi++)
            afr[mi] = *(const bf16x8*)&As[buf][(wm * 32 + mi * 16 + row16) * 32 + fchunk];
#pragma unroll
        for (int ni = 0; ni < 2; ni++)
            bfr[ni] = *(const bf16x8*)&Bs[buf][(wn * 32 + ni * 16 + row16) * 32 + fchunk];
#pragma unroll
        for (int mi = 0; mi < 2; mi++)
#pragma unroll
            for (int ni = 0; ni < 2; ni++)
                acc[mi][ni] = __builtin_amdgcn_mfma_f32_16x16x32_bf16(
                    afr[mi], bfr[ni], acc[mi][ni], 0, 0, 0);
    }

    // epilogue: atomic accumulate into out[b][q][f]  (n = b*16+f)
#pragma unroll
    for (int mi = 0; mi < 2; mi++)
#pragma unroll
        for (int ni = 0; ni < 2; ni++) {
            int n = n0 + wn * 32 + ni * 16 + row16;
            float* o = out + (size_t)(n >> 4) * (NQ * REL_D) + (n & 15);
#pragma unroll
            for (int r = 0; r < 4; r++) {
                int q = q0 + wm * 32 + mi * 16 + quad * 4 + r;
                atomicAdd(o + q * REL_D, acc[mi][ni][r]);
            }
        }
}

extern "C" void kernel_launch(void* const* d_in, const int* in_sizes, int n_in,
                              void* d_out, int out_size, void* d_ws, size_t ws_size,
                              hipStream_t stream) {
    const float* inputs  = (const float*)d_in[0];   // (32,32,32,16)
    const float* logits  = (const float*)d_in[1];   // (512,32)
    const float* filters = (const float*)d_in[2];   // (16,3,3,16)
    float* out = (float*)d_out;                     // (32,512,16)

    char* ws = (char*)d_ws;
    unsigned short* normw = (unsigned short*)ws;                 //  5,242,880 B
    unsigned short* D     = (unsigned short*)(ws + 5242880);     //  9,437,184 B
    unsigned short* relT  = (unsigned short*)(ws + 14680064);    //  5,242,880 B

    k_front<<<NQ + 1152 + 16, 256, 0, stream>>>(logits, inputs, filters, normw, D, relT, out);
    k_mid<<<G_TOTAL / 8, 256, 0, stream>>>(D, relT);
    k_gemm<<<dim3(8, 8, ZSPLIT), 256, 0, stream>>>(normw, relT, out);
}